// Round 9
// baseline (279.830 us; speedup 1.0000x reference)
//
#include <hip/hip_runtime.h>
#include <hip/hip_bf16.h>

// Problem constants
#define BB   2
#define SEQ  2048
#define DIMD 2048
#define NHH  32
#define NKVV 8
#define HDD  64
#define QKVS 3072
// N_REP = 4

typedef __bf16 bf16x8 __attribute__((ext_vector_type(8)));
typedef float  floatx4  __attribute__((ext_vector_type(4)));
typedef float  floatx16 __attribute__((ext_vector_type(16)));

typedef __attribute__((address_space(1))) const void* gas_ptr;
typedef __attribute__((address_space(3))) void*       las_ptr;

#define MFMA16 __builtin_amdgcn_mfma_f32_16x16x32_bf16
#define MFMA32 __builtin_amdgcn_mfma_f32_32x32x16_bf16
#define CBAR() asm volatile("" ::: "memory")
#define EXP2F(x) __builtin_amdgcn_exp2f(x)

__device__ __forceinline__ unsigned short f2bu(float f) {
    __hip_bfloat16 h = __float2bfloat16(f);
    return *reinterpret_cast<unsigned short*>(&h);
}

// DPP lane-move within 16-lane rows (all lanes active).
#define DPPF(x, ctrl) __int_as_float(__builtin_amdgcn_mov_dpp(__float_as_int(x), (ctrl), 0xF, 0xF, true))
__device__ __forceinline__ float red16_max(float x) {
    x = fmaxf(x, DPPF(x, 0xB1));
    x = fmaxf(x, DPPF(x, 0x4E));
    x = fmaxf(x, DPPF(x, 0x124));
    x = fmaxf(x, DPPF(x, 0x128));
    return x;
}
__device__ __forceinline__ float red16_sum(float x) {
    x += DPPF(x, 0xB1);
    x += DPPF(x, 0x4E);
    x += DPPF(x, 0x124);
    x += DPPF(x, 0x128);
    return x;
}

// ---------------------------------------------------------------------------
// Fused f32 -> bf16 conversion for all 5 inputs (one launch).
// ---------------------------------------------------------------------------
#define C_X  (8u  * 1024 * 1024)
#define C_WQ (4u  * 1024 * 1024)
#define C_WK (1u  * 1024 * 1024)
#define C_WV (1u  * 1024 * 1024)
#define C_WO (4u  * 1024 * 1024)
__global__ void cvt_all(const float* __restrict__ x,  const float* __restrict__ wq,
                        const float* __restrict__ wk, const float* __restrict__ wv,
                        const float* __restrict__ wo,
                        __hip_bfloat16* __restrict__ xb,
                        __hip_bfloat16* __restrict__ wqkv,
                        __hip_bfloat16* __restrict__ wob)
{
    unsigned i = (blockIdx.x * blockDim.x + threadIdx.x) * 4;
    const float* src; __hip_bfloat16* dst;
    if (i < C_X)                       { src = x  + i;                    dst = xb + i; }
    else if (i < C_X + C_WQ)           { unsigned o = i - C_X;            src = wq + o; dst = wqkv + o; }
    else if (i < C_X + C_WQ + C_WK)    { unsigned o = i - C_X - C_WQ;     src = wk + o; dst = wqkv + C_WQ + o; }
    else if (i < C_X + C_WQ + C_WK + C_WV) { unsigned o = i - C_X - C_WQ - C_WK; src = wv + o; dst = wqkv + C_WQ + C_WK + o; }
    else                               { unsigned o = i - C_X - C_WQ - C_WK - C_WV; if (o >= C_WO) return; src = wo + o; dst = wob + o; }
    float4 v = *reinterpret_cast<const float4*>(src);
    dst[0] = __float2bfloat16(v.x);
    dst[1] = __float2bfloat16(v.y);
    dst[2] = __float2bfloat16(v.z);
    dst[3] = __float2bfloat16(v.w);
}

// ---------------------------------------------------------------------------
// GEMM, 32x32x16 MFMA, BK=64, round-7 LDS layout (rows of 64 elem = 128B,
// chunk ch = chL ^ (row&7), source pre-swizzled, linear gload_lds dest).
// NEW: block tile 128x256, wave-tile 64x128 (2M x 2N waves, acc[2][4]):
// 6 ds_read per 8 MFMA (was 1:1), 32 MFMA per barrier-pair (was 16).
// LDS 48KB, launch_bounds(256,3) -> 3 blocks/CU.
// ROPE=true: RoPE epilogue for cols < 2560 (q|k); cols >= 2560 (V) written
// TRANSPOSED directly to vT[b][kvh][d][s]. Wave spans 2 heads (128 cols).
// C/D layout (HW-verified m74/m101): col=lane&31, row=(reg&3)+8*(reg>>2)+4*(lane>>5).
// ---------------------------------------------------------------------------
template <typename OutT, bool ROPE>
__global__ __launch_bounds__(256, 3) void gemm32(
    const __hip_bfloat16* __restrict__ Abf,
    const __hip_bfloat16* __restrict__ Wbf,
    OutT* __restrict__ C,
    int M, int N, int K, int ldc,
    const float* __restrict__ cosb, const float* __restrict__ sinb,
    unsigned short* __restrict__ vT)
{
    const __bf16* A = reinterpret_cast<const __bf16*>(Abf);
    const __bf16* W = reinterpret_cast<const __bf16*>(Wbf);

    __shared__ __bf16 As[128 * 64];   // 16 KB
    __shared__ __bf16 Bs[256 * 64];   // 32 KB

    int tid  = threadIdx.x;
    int wid  = tid >> 6;
    int lane = tid & 63;
    int l31  = lane & 31;
    int lh   = lane >> 5;
    int wm   = (wid >> 1) * 64;       // 2 M-waves, 64 rows each
    int wn   = (wid & 1) * 128;       // 2 N-waves, 128 cols each
    int bm   = blockIdx.x * 128;
    int bn   = blockIdx.y * 256;

    // Staging (round-7 pattern): slot -> {row = slot>>3, 16B chunk slot&7};
    // source chunk pre-swizzled g = (slot&7) ^ (row&7). Since row steps by 32
    // between load groups, the swizzled column is invariant across i.
    int r0 = tid >> 3;
    int c0 = ((tid & 7) ^ (r0 & 7)) * 8;
    const __bf16* aB = A + (size_t)(bm + r0) * K + c0;
    const __bf16* wB = W + (size_t)(bn + r0) * K + c0;

    floatx16 acc[2][4] = {};

    for (int k0 = 0; k0 < K; k0 += 64) {
        #pragma unroll
        for (int i = 0; i < 4; ++i)
            __builtin_amdgcn_global_load_lds((gas_ptr)(aB + (size_t)(32 * i) * K + k0),
                (las_ptr)(As + (tid + 256 * i) * 8), 16, 0, 0);
        #pragma unroll
        for (int i = 0; i < 8; ++i)
            __builtin_amdgcn_global_load_lds((gas_ptr)(wB + (size_t)(32 * i) * K + k0),
                (las_ptr)(Bs + (tid + 256 * i) * 8), 16, 0, 0);
        __syncthreads();

        #pragma unroll
        for (int s = 0; s < 4; ++s) {            // 4 k-steps of 16
            int chL = s * 2 + lh;                // lane's 16B chunk (0..7)
            bf16x8 af[2], bfr[4];
            #pragma unroll
            for (int mt = 0; mt < 2; ++mt) {
                int row = wm + mt * 32 + l31;
                int ch  = chL ^ (row & 7);
                af[mt] = *reinterpret_cast<const bf16x8*>(As + row * 64 + ch * 8);
            }
            #pragma unroll
            for (int nt = 0; nt < 4; ++nt) {
                int row = wn + nt * 32 + l31;
                int ch  = chL ^ (row & 7);
                bfr[nt] = *reinterpret_cast<const bf16x8*>(Bs + row * 64 + ch * 8);
            }
            #pragma unroll
            for (int mt = 0; mt < 2; ++mt)
                #pragma unroll
                for (int nt = 0; nt < 4; ++nt)
                    acc[mt][nt] = MFMA32(af[mt], bfr[nt], acc[mt][nt], 0, 0, 0);
        }
        __syncthreads();
    }

    const int col0 = bn + wn;                    // wave col base (128 wide)
    if constexpr (ROPE) {
        if (col0 >= 2560) {
            // V section: wave covers 2 kv-heads; write transposed to vT.
            int b = bm >> 11;
            #pragma unroll
            for (int mt = 0; mt < 2; ++mt)
                #pragma unroll
                for (int rq = 0; rq < 4; ++rq) {
                    int s0 = (bm & (SEQ - 1)) + wm + mt * 32 + rq * 8 + lh * 4;
                    #pragma unroll
                    for (int nt = 0; nt < 4; ++nt) {
                        int dg  = col0 - 2560 + nt * 32 + l31;
                        int kvh = dg >> 6;
                        int d   = dg & 63;
                        ushort4 u;
                        u.x = f2bu(acc[mt][nt][rq * 4 + 0]);
                        u.y = f2bu(acc[mt][nt][rq * 4 + 1]);
                        u.z = f2bu(acc[mt][nt][rq * 4 + 2]);
                        u.w = f2bu(acc[mt][nt][rq * 4 + 3]);
                        *reinterpret_cast<ushort4*>(
                            vT + ((size_t)(b * NKVV + kvh) * 64 + d) * SEQ + s0) = u;
                    }
                }
        } else {
            // q|k: wave covers 2 heads; RoPE pairs (d,d+32) = (nt, nt+1), nt even
            #pragma unroll
            for (int mt = 0; mt < 2; ++mt)
                #pragma unroll
                for (int np = 0; np < 2; ++np) {     // head pair index
                    int nt = np * 2;
                    #pragma unroll
                    for (int reg = 0; reg < 16; ++reg) {
                        int row = bm + wm + mt * 32 + (reg & 3) + (reg >> 2) * 8 + lh * 4;
                        int s   = row & (SEQ - 1);
                        float x1 = acc[mt][nt][reg], x2 = acc[mt][nt + 1][reg];
                        float cf = cosb[s * 32 + l31];
                        float sf = sinb[s * 32 + l31];
                        float o1 = x1 * cf - x2 * sf;
                        float o2 = x2 * cf + x1 * sf;
                        C[(size_t)row * ldc + col0 + nt * 32 + l31]      = __float2bfloat16(o1);
                        C[(size_t)row * ldc + col0 + nt * 32 + 32 + l31] = __float2bfloat16(o2);
                    }
                }
        }
    } else {
        #pragma unroll
        for (int mt = 0; mt < 2; ++mt)
            #pragma unroll
            for (int nt = 0; nt < 4; ++nt)
                #pragma unroll
                for (int reg = 0; reg < 16; ++reg) {
                    int row = bm + wm + mt * 32 + (reg & 3) + (reg >> 2) * 8 + lh * 4;
                    int col = col0 + nt * 32 + l31;
                    if constexpr (sizeof(OutT) == 4)
                        C[(size_t)row * ldc + col] = acc[mt][nt][reg];
                    else
                        C[(size_t)row * ldc + col] = __float2bfloat16(acc[mt][nt][reg]);
                }
    }
}

// ---------------------------------------------------------------------------
// MFMA flash attention, doc+causal. dbuf staging (counted vmcnt), hoisted
// K/V frags, DPP reductions, exp2 domain, -3e30 mask, full-valid fast path.
// (unchanged — proven at 257.8 µs)
// ---------------------------------------------------------------------------
#define SCL2 0.18033688f   // 0.125 * log2(e)
#define MASKV -3e30f

__global__ __launch_bounds__(256) void attn_mfma(
    const __hip_bfloat16* __restrict__ qkv,  // [B*S][3072]: q | k | (v unused)
    const unsigned short* __restrict__ vT,   // [B][NKV][64][S]
    const int* __restrict__ doc,             // [B][S]
    __hip_bfloat16* __restrict__ ob)         // [B*S][NH*64]
{
    int qblk = (int)gridDim.x - 1 - (int)blockIdx.x;   // heavy blocks first
    int h    = blockIdx.y;
    int b    = blockIdx.z;
    int kvh  = h >> 2;
    int tid  = threadIdx.x;
    int wv   = tid >> 6;
    int lane = tid & 63;
    int l15  = lane & 15;
    int l4   = lane >> 4;
    int q0   = qblk * 128;
    int qw   = q0 + wv * 32;

    __shared__ unsigned short Ks[2][64 * 64];    // [key][dim], swizzled chunks
    __shared__ unsigned short Vts[2][64 * 64];   // [dim][key], swizzled chunks
    __shared__ int            kdoc[2][64];
    __shared__ unsigned short Pb[4][32][76];     // per-wave P tile

    const unsigned short* qus = reinterpret_cast<const unsigned short*>(qkv);
    const unsigned short* kus = qus + 2048;
    const int* docb = doc + b * SEQ;

    bf16x8 aq[2][2];
    #pragma unroll
    for (int qt = 0; qt < 2; ++qt) {
        const unsigned short* qrow = qus + (size_t)(b * SEQ + qw + qt * 16 + l15) * QKVS + h * HDD;
        aq[qt][0] = *reinterpret_cast<const bf16x8*>(qrow + l4 * 8);
        aq[qt][1] = *reinterpret_cast<const bf16x8*>(qrow + 32 + l4 * 8);
    }
    int qd[2][4];
    #pragma unroll
    for (int qt = 0; qt < 2; ++qt)
        #pragma unroll
        for (int r = 0; r < 4; ++r)
            qd[qt][r] = docb[qw + qt * 16 + l4 * 4 + r];
    int qd_w   = docb[qw];
    int qd_w31 = docb[qw + 31];
    int qd_blk = docb[q0];
    bool qdu   = (qd_w == qd_w31);

    float mrow[2][4], lrow[2][4];
    #pragma unroll
    for (int qt = 0; qt < 2; ++qt)
        #pragma unroll
        for (int r = 0; r < 4; ++r) { mrow[qt][r] = -1e30f; lrow[qt][r] = 0.f; }
    floatx4 accO[2][4] = {};

    int slot0 = tid, slot1 = tid + 256;
    int row0 = slot0 >> 3, g0 = (slot0 & 7) ^ (row0 & 7);
    int row1 = slot1 >> 3, g1 = (slot1 & 7) ^ (row1 & 7);
    const unsigned short* vtb = vT + ((size_t)(b * NKVV + kvh) * 64) * SEQ;

    // ---- valid-chunk bitmap (chunks 0..kc_end with doc overlap)
    int kc_end = 2 * qblk + 1;                    // <= 31
    unsigned mask;
    {
        bool v = false;
        if (lane <= kc_end && lane < 32)
            v = (docb[lane * 64 + 63] >= qd_blk);
        mask = (unsigned)__ballot(v);
    }

    auto stagec = [&](int buf, int kc) {
        int k0 = kc * 64;
        __builtin_amdgcn_global_load_lds(
            (gas_ptr)(kus + (size_t)(b * SEQ + k0 + row0) * QKVS + kvh * HDD + g0 * 8),
            (las_ptr)(&Ks[buf][slot0 * 8]), 16, 0, 0);
        __builtin_amdgcn_global_load_lds(
            (gas_ptr)(kus + (size_t)(b * SEQ + k0 + row1) * QKVS + kvh * HDD + g1 * 8),
            (las_ptr)(&Ks[buf][slot1 * 8]), 16, 0, 0);
        __builtin_amdgcn_global_load_lds(
            (gas_ptr)(vtb + (size_t)row0 * SEQ + k0 + g0 * 8),
            (las_ptr)(&Vts[buf][slot0 * 8]), 16, 0, 0);
        __builtin_amdgcn_global_load_lds(
            (gas_ptr)(vtb + (size_t)row1 * SEQ + k0 + g1 * 8),
            (las_ptr)(&Vts[buf][slot1 * 8]), 16, 0, 0);
        __builtin_amdgcn_global_load_lds(
            (gas_ptr)(docb + k0 + lane),
            (las_ptr)(&kdoc[buf][lane]), 4, 0, 0);
    };

    int p  = 0;
    int kc = (int)__builtin_ctz(mask);
    mask &= mask - 1;
    stagec(0, kc);

    while (true) {
        int nkc = -1;
        if (mask) {
            nkc = (int)__builtin_ctz(mask);
            mask &= mask - 1;
            stagec(p ^ 1, nkc);
            asm volatile("s_waitcnt vmcnt(5)" ::: "memory");
        } else {
            asm volatile("s_waitcnt vmcnt(0)" ::: "memory");
        }
        CBAR(); __builtin_amdgcn_s_barrier(); CBAR();

        int k0 = kc * 64;
        int kd_first = kdoc[p][0];
        int kd_last  = kdoc[p][63];
        if (k0 <= qw + 31 && kd_last >= qd_w) {   // wave-uniform compute skip
            bool full = qdu && (kd_first == kd_last) && (kd_last == qd_w)
                        && (k0 + 64 <= qw);

            // hoisted K fragments (8 ds_read_b128, shared by both qt)
            bf16x8 bk[4][2];
            #pragma unroll
            for (int t = 0; t < 4; ++t) {
                int krow = t * 16 + l15;
                bk[t][0] = *reinterpret_cast<const bf16x8*>(&Ks[p][krow * 64 + ((l4 ^ (krow & 7)) * 8)]);
                bk[t][1] = *reinterpret_cast<const bf16x8*>(&Ks[p][krow * 64 + (((l4 + 4) ^ (krow & 7)) * 8)]);
            }

            #pragma unroll
            for (int qt = 0; qt < 2; ++qt) {
                float s[4][4];
                #pragma unroll
                for (int t = 0; t < 4; ++t) {
                    floatx4 a = {};
                    a = MFMA16(aq[qt][0], bk[t][0], a, 0, 0, 0);
                    a = MFMA16(aq[qt][1], bk[t][1], a, 0, 0, 0);
                    if (full) {
                        #pragma unroll
                        for (int r = 0; r < 4; ++r) s[t][r] = a[r] * SCL2;
                    } else {
                        int key = k0 + t * 16 + l15;
                        int kd  = kdoc[p][t * 16 + l15];
                        #pragma unroll
                        for (int r = 0; r < 4; ++r) {
                            int qrow = qw + qt * 16 + l4 * 4 + r;
                            bool valid = (kd == qd[qt][r]) && (key <= qrow);
                            s[t][r] = valid ? a[r] * SCL2 : MASKV;
                        }
                    }
                }
                #pragma unroll
                for (int r = 0; r < 4; ++r) {
                    float pm = fmaxf(fmaxf(s[0][r], s[1][r]), fmaxf(s[2][r], s[3][r]));
                    pm = red16_max(pm);
                    float mnew = fmaxf(mrow[qt][r], pm);
                    float alpha = EXP2F(mrow[qt][r] - mnew);
                    mrow[qt][r] = mnew;
                    float ps = 0.f;
                    #pragma unroll
                    for (int t = 0; t < 4; ++t) {
                        float pv = EXP2F(s[t][r] - mnew);   // masked -> underflow 0
                        Pb[wv][qt * 16 + l4 * 4 + r][t * 16 + l15] = f2bu(pv);
                        ps += pv;
                    }
                    ps = red16_sum(ps);
                    lrow[qt][r] = lrow[qt][r] * alpha + ps;
                    #pragma unroll
                    for (int t = 0; t < 4; ++t) accO[qt][t][r] *= alpha;
                }
            }

            // hoisted V fragments (8 ds_read_b128, shared by both qt)
            bf16x8 bvf[4][2];
            #pragma unroll
            for (int t = 0; t < 4; ++t) {
                int vrow = t * 16 + l15;
                bvf[t][0] = *reinterpret_cast<const bf16x8*>(&Vts[p][vrow * 64 + ((l4 ^ (vrow & 7)) * 8)]);
                bvf[t][1] = *reinterpret_cast<const bf16x8*>(&Vts[p][vrow * 64 + (((l4 + 4) ^ (vrow & 7)) * 8)]);
            }
            #pragma unroll
            for (int qt = 0; qt < 2; ++qt) {
                bf16x8 ap0 = *reinterpret_cast<const bf16x8*>(&Pb[wv][qt * 16 + l15][l4 * 8]);
                bf16x8 ap1 = *reinterpret_cast<const bf16x8*>(&Pb[wv][qt * 16 + l15][32 + l4 * 8]);
                #pragma unroll
                for (int t = 0; t < 4; ++t) {
                    accO[qt][t] = MFMA16(ap0, bvf[t][0], accO[qt][t], 0, 0, 0);
                    accO[qt][t] = MFMA16(ap1, bvf[t][1], accO[qt][t], 0, 0, 0);
                }
            }
        }
        CBAR(); __builtin_amdgcn_s_barrier(); CBAR();
        if (nkc < 0) break;
        kc = nkc; p ^= 1;
    }

    #pragma unroll
    for (int qt = 0; qt < 2; ++qt)
        #pragma unroll
        for (int r = 0; r < 4; ++r) {
            float inv = 1.0f / lrow[qt][r];
            size_t base = (size_t)(b * SEQ + qw + qt * 16 + l4 * 4 + r) * (NHH * HDD) + h * HDD;
            #pragma unroll
            for (int t = 0; t < 4; ++t)
                ob[base + t * 16 + l15] = __float2bfloat16(accO[qt][t][r] * inv);
        }
}

// ---------------------------------------------------------------------------
extern "C" void kernel_launch(void* const* d_in, const int* in_sizes, int n_in,
                              void* d_out, int out_size, void* d_ws, size_t ws_size,
                              hipStream_t stream) {
    const float* x  = (const float*)d_in[0];
    const float* rc = (const float*)d_in[1];
    const float* rs = (const float*)d_in[2];
    const int*   dc = (const int*)d_in[3];
    const float* Wq = (const float*)d_in[4];
    const float* Wk = (const float*)d_in[5];
    const float* Wv = (const float*)d_in[6];
    const float* Wo = (const float*)d_in[7];
    float* out = (float*)d_out;

    const int M    = BB * SEQ;        // 4096
    const int KVD  = NKVV * HDD;      // 512
    const int QKVN = DIMD + 2 * KVD;  // 3072

    char* ws = (char*)d_ws;
    size_t off = 0;
    auto alloc = [&](size_t elems) { __hip_bfloat16* p = (__hip_bfloat16*)(ws + off); off += elems * 2; return p; };
    __hip_bfloat16* xb   = alloc((size_t)M * DIMD);      // 16 MB
    __hip_bfloat16* wqkv = alloc((size_t)QKVN * DIMD);   // 12 MB
    __hip_bfloat16* wob  = alloc((size_t)DIMD * DIMD);   //  8 MB
    __hip_bfloat16* qkv  = alloc((size_t)M * QKVN);      // 24 MB (v-section unused)
    __hip_bfloat16* abuf = alloc((size_t)M * DIMD);      // 16 MB
    unsigned short* vtb  = (unsigned short*)alloc((size_t)BB * NKVV * HDD * SEQ); // 4 MB

    // one fused f32->bf16 conversion launch
    {
        unsigned total4 = (C_X + C_WQ + C_WK + C_WV + C_WO) / 4;
        cvt_all<<<dim3((total4 + 255) / 256), 256, 0, stream>>>(
            x, Wq, Wk, Wv, Wo, xb, wqkv, wob);
    }

    // fused QKV projection: RoPE epilogue + direct V-transpose to vT
    gemm32<__hip_bfloat16, true><<<dim3(M / 128, QKVN / 256), 256, 0, stream>>>(
        xb, wqkv, qkv, M, QKVN, DIMD, QKVN, rc, rs, vtb);

    // attention (MFMA, doc-skip, dbuf staging, DPP softmax)
    attn_mfma<<<dim3(SEQ / 128, NHH, BB), 256, 0, stream>>>(qkv, vtb, dc, abuf);

    // output projection (f32 out): grid 32x8 = 256 blocks = exact CU fill
    gemm32<float, false><<<dim3(M / 128, DIMD / 256), 256, 0, stream>>>(
        abuf, wob, out, M, DIMD, DIMD, DIMD, nullptr, nullptr, nullptr);
}

// Round 10
// 275.478 us; speedup vs baseline: 1.0158x; 1.0158x over previous
//
#include <hip/hip_runtime.h>
#include <hip/hip_bf16.h>

// Problem constants
#define BB   2
#define SEQ  2048
#define DIMD 2048
#define NHH  32
#define NKVV 8
#define HDD  64
#define QKVS 3072
// N_REP = 4

typedef __bf16 bf16x8 __attribute__((ext_vector_type(8)));
typedef float  floatx4  __attribute__((ext_vector_type(4)));
typedef float  floatx16 __attribute__((ext_vector_type(16)));

typedef __attribute__((address_space(1))) const void* gas_ptr;
typedef __attribute__((address_space(3))) void*       las_ptr;

#define MFMA16 __builtin_amdgcn_mfma_f32_16x16x32_bf16
#define MFMA32 __builtin_amdgcn_mfma_f32_32x32x16_bf16
#define CBAR() asm volatile("" ::: "memory")
#define EXP2F(x) __builtin_amdgcn_exp2f(x)

__device__ __forceinline__ unsigned short f2bu(float f) {
    __hip_bfloat16 h = __float2bfloat16(f);
    return *reinterpret_cast<unsigned short*>(&h);
}

// DPP lane-move within 16-lane rows (all lanes active).
#define DPPF(x, ctrl) __int_as_float(__builtin_amdgcn_mov_dpp(__float_as_int(x), (ctrl), 0xF, 0xF, true))
__device__ __forceinline__ float red16_max(float x) {
    x = fmaxf(x, DPPF(x, 0xB1));
    x = fmaxf(x, DPPF(x, 0x4E));
    x = fmaxf(x, DPPF(x, 0x124));
    x = fmaxf(x, DPPF(x, 0x128));
    return x;
}
__device__ __forceinline__ float red16_sum(float x) {
    x += DPPF(x, 0xB1);
    x += DPPF(x, 0x4E);
    x += DPPF(x, 0x124);
    x += DPPF(x, 0x128);
    return x;
}

// ---------------------------------------------------------------------------
// Fused f32 -> bf16 conversion for all 5 inputs (one launch).
// ---------------------------------------------------------------------------
#define C_X  (8u  * 1024 * 1024)
#define C_WQ (4u  * 1024 * 1024)
#define C_WK (1u  * 1024 * 1024)
#define C_WV (1u  * 1024 * 1024)
#define C_WO (4u  * 1024 * 1024)
__global__ void cvt_all(const float* __restrict__ x,  const float* __restrict__ wq,
                        const float* __restrict__ wk, const float* __restrict__ wv,
                        const float* __restrict__ wo,
                        __hip_bfloat16* __restrict__ xb,
                        __hip_bfloat16* __restrict__ wqkv,
                        __hip_bfloat16* __restrict__ wob)
{
    unsigned i = (blockIdx.x * blockDim.x + threadIdx.x) * 4;
    const float* src; __hip_bfloat16* dst;
    if (i < C_X)                       { src = x  + i;                    dst = xb + i; }
    else if (i < C_X + C_WQ)           { unsigned o = i - C_X;            src = wq + o; dst = wqkv + o; }
    else if (i < C_X + C_WQ + C_WK)    { unsigned o = i - C_X - C_WQ;     src = wk + o; dst = wqkv + C_WQ + o; }
    else if (i < C_X + C_WQ + C_WK + C_WV) { unsigned o = i - C_X - C_WQ - C_WK; src = wv + o; dst = wqkv + C_WQ + C_WK + o; }
    else                               { unsigned o = i - C_X - C_WQ - C_WK - C_WV; if (o >= C_WO) return; src = wo + o; dst = wob + o; }
    float4 v = *reinterpret_cast<const float4*>(src);
    dst[0] = __float2bfloat16(v.x);
    dst[1] = __float2bfloat16(v.y);
    dst[2] = __float2bfloat16(v.z);
    dst[3] = __float2bfloat16(v.w);
}

// ---------------------------------------------------------------------------
// GEMM (round-7 proven, 257.8 us config): 32x32x16 MFMA + BK=64, 128B rows,
// chunk swizzle ch = chL ^ (row&7), source pre-swizzled, linear gload dest.
// C[M,ldc] = A[M,K] @ W[N,K]^T, bf16 in, f32 acc. Wave-tile 64x64. LDS 32KB.
// ROPE=true: RoPE epilogue for cols < 2560 (q|k); cols >= 2560 (V) written
// TRANSPOSED directly to vT[b][kvh][d][s].
// C/D layout (HW-verified m74/m101): col=lane&31, row=(reg&3)+8*(reg>>2)+4*(lane>>5).
// ---------------------------------------------------------------------------
template <typename OutT, bool ROPE>
__global__ __launch_bounds__(256) void gemm32(
    const __hip_bfloat16* __restrict__ Abf,
    const __hip_bfloat16* __restrict__ Wbf,
    OutT* __restrict__ C,
    int M, int N, int K, int ldc,
    const float* __restrict__ cosb, const float* __restrict__ sinb,
    unsigned short* __restrict__ vT)
{
    const __bf16* A = reinterpret_cast<const __bf16*>(Abf);
    const __bf16* W = reinterpret_cast<const __bf16*>(Wbf);

    __shared__ __bf16 As[128 * 64];   // 16 KB
    __shared__ __bf16 Bs[128 * 64];   // 16 KB

    int tid  = threadIdx.x;
    int wid  = tid >> 6;
    int lane = tid & 63;
    int l31  = lane & 31;
    int lh   = lane >> 5;
    int wm   = (wid & 1) * 64;
    int wn   = (wid >> 1) * 64;
    int bm   = blockIdx.x * 128;
    int bn   = blockIdx.y * 128;

    // Staging: 4 x 16B loads per thread per matrix; LDS dest linear
    // (slot*16B); source chunk pre-XOR-swizzled with (row&7).
    const __bf16* aS[4]; const __bf16* wS[4];
    #pragma unroll
    for (int i = 0; i < 4; ++i) {
        int slot = tid + 256 * i;
        int r = slot >> 3;
        int c = (slot & 7) ^ (r & 7);
        aS[i] = A + (size_t)(bm + r) * K + c * 8;
        wS[i] = W + (size_t)(bn + r) * K + c * 8;
    }

    floatx16 acc[2][2] = {};

    for (int k0 = 0; k0 < K; k0 += 64) {
        #pragma unroll
        for (int i = 0; i < 4; ++i)
            __builtin_amdgcn_global_load_lds((gas_ptr)(aS[i] + k0),
                (las_ptr)(As + (tid + 256 * i) * 8), 16, 0, 0);
        #pragma unroll
        for (int i = 0; i < 4; ++i)
            __builtin_amdgcn_global_load_lds((gas_ptr)(wS[i] + k0),
                (las_ptr)(Bs + (tid + 256 * i) * 8), 16, 0, 0);
        __syncthreads();

        #pragma unroll
        for (int s = 0; s < 4; ++s) {            // 4 k-steps of 16
            bf16x8 af[2], bfr[2];
            #pragma unroll
            for (int mt = 0; mt < 2; ++mt) {
                int row = wm + mt * 32 + l31;
                int ch  = (s * 2 + lh) ^ (row & 7);
                af[mt] = *reinterpret_cast<const bf16x8*>(As + row * 64 + ch * 8);
            }
            #pragma unroll
            for (int nt = 0; nt < 2; ++nt) {
                int row = wn + nt * 32 + l31;
                int ch  = (s * 2 + lh) ^ (row & 7);
                bfr[nt] = *reinterpret_cast<const bf16x8*>(Bs + row * 64 + ch * 8);
            }
            #pragma unroll
            for (int mt = 0; mt < 2; ++mt)
                #pragma unroll
                for (int nt = 0; nt < 2; ++nt)
                    acc[mt][nt] = MFMA32(af[mt], bfr[nt], acc[mt][nt], 0, 0, 0);
        }
        __syncthreads();
    }

    const int col0 = bn + wn;
    if constexpr (ROPE) {
        if (col0 >= 2560) {
            // V section: write transposed directly to vT[b][kvh][d][s].
            int kvh = (col0 - 2560) >> 6;
            int b   = bm >> 11;
            #pragma unroll
            for (int mt = 0; mt < 2; ++mt)
                #pragma unroll
                for (int rq = 0; rq < 4; ++rq) {
                    int s0 = (bm & (SEQ - 1)) + wm + mt * 32 + rq * 8 + lh * 4;
                    #pragma unroll
                    for (int nt = 0; nt < 2; ++nt) {
                        int d = nt * 32 + l31;
                        ushort4 u;
                        u.x = f2bu(acc[mt][nt][rq * 4 + 0]);
                        u.y = f2bu(acc[mt][nt][rq * 4 + 1]);
                        u.z = f2bu(acc[mt][nt][rq * 4 + 2]);
                        u.w = f2bu(acc[mt][nt][rq * 4 + 3]);
                        *reinterpret_cast<ushort4*>(
                            vT + ((size_t)(b * NKVV + kvh) * 64 + d) * SEQ + s0) = u;
                    }
                }
        } else {
            // q|k section: RoPE pairs (d, d+32) = (acc[mt][0], acc[mt][1]), d = l31
            #pragma unroll
            for (int mt = 0; mt < 2; ++mt)
                #pragma unroll
                for (int reg = 0; reg < 16; ++reg) {
                    int row = bm + wm + mt * 32 + (reg & 3) + (reg >> 2) * 8 + lh * 4;
                    int s   = row & (SEQ - 1);
                    float x1 = acc[mt][0][reg], x2 = acc[mt][1][reg];
                    float cf = cosb[s * 32 + l31];
                    float sf = sinb[s * 32 + l31];
                    float o1 = x1 * cf - x2 * sf;
                    float o2 = x2 * cf + x1 * sf;
                    C[(size_t)row * ldc + col0 + l31]      = __float2bfloat16(o1);
                    C[(size_t)row * ldc + col0 + 32 + l31] = __float2bfloat16(o2);
                }
        }
    } else {
        #pragma unroll
        for (int mt = 0; mt < 2; ++mt)
            #pragma unroll
            for (int nt = 0; nt < 2; ++nt)
                #pragma unroll
                for (int reg = 0; reg < 16; ++reg) {
                    int row = bm + wm + mt * 32 + (reg & 3) + (reg >> 2) * 8 + lh * 4;
                    int col = col0 + nt * 32 + l31;
                    if constexpr (sizeof(OutT) == 4)
                        C[(size_t)row * ldc + col] = acc[mt][nt][reg];
                    else
                        C[(size_t)row * ldc + col] = __float2bfloat16(acc[mt][nt][reg]);
                }
    }
}

// ---------------------------------------------------------------------------
// MFMA flash attention, doc+causal. NEW: 2 heads per block (same kvh) —
// K/V staging + bk/bvf fragments shared by both heads, per-chunk compute
// doubled (latency cover), staging traffic and chunk-loop overhead halved.
// dbuf staging (counted vmcnt), DPP reductions, exp2 domain, -3e30 mask,
// full-valid fast path. Pb reused sequentially per head (per-wave buffer).
// ---------------------------------------------------------------------------
#define SCL2 0.18033688f   // 0.125 * log2(e)
#define MASKV -3e30f

__global__ __launch_bounds__(256) void attn_mfma(
    const __hip_bfloat16* __restrict__ qkv,  // [B*S][3072]: q | k | (v unused)
    const unsigned short* __restrict__ vT,   // [B][NKV][64][S]
    const int* __restrict__ doc,             // [B][S]
    __hip_bfloat16* __restrict__ ob)         // [B*S][NH*64]
{
    int qblk = (int)gridDim.x - 1 - (int)blockIdx.x;   // heavy blocks first
    int h0   = blockIdx.y * 2;                         // head pair (same kvh)
    int b    = blockIdx.z;
    int kvh  = h0 >> 2;
    int tid  = threadIdx.x;
    int wv   = tid >> 6;
    int lane = tid & 63;
    int l15  = lane & 15;
    int l4   = lane >> 4;
    int q0   = qblk * 128;
    int qw   = q0 + wv * 32;

    __shared__ unsigned short Ks[2][64 * 64];    // [key][dim], swizzled chunks
    __shared__ unsigned short Vts[2][64 * 64];   // [dim][key], swizzled chunks
    __shared__ int            kdoc[2][64];
    __shared__ unsigned short Pb[4][32][76];     // per-wave P tile (reused per head)

    const unsigned short* qus = reinterpret_cast<const unsigned short*>(qkv);
    const unsigned short* kus = qus + 2048;
    const int* docb = doc + b * SEQ;

    bf16x8 aq[2][2][2];                          // [head][qt][half]
    #pragma unroll
    for (int hd = 0; hd < 2; ++hd)
        #pragma unroll
        for (int qt = 0; qt < 2; ++qt) {
            const unsigned short* qrow = qus + (size_t)(b * SEQ + qw + qt * 16 + l15) * QKVS + (h0 + hd) * HDD;
            aq[hd][qt][0] = *reinterpret_cast<const bf16x8*>(qrow + l4 * 8);
            aq[hd][qt][1] = *reinterpret_cast<const bf16x8*>(qrow + 32 + l4 * 8);
        }
    int qd[2][4];
    #pragma unroll
    for (int qt = 0; qt < 2; ++qt)
        #pragma unroll
        for (int r = 0; r < 4; ++r)
            qd[qt][r] = docb[qw + qt * 16 + l4 * 4 + r];
    int qd_w   = docb[qw];
    int qd_w31 = docb[qw + 31];
    int qd_blk = docb[q0];
    bool qdu   = (qd_w == qd_w31);

    float mrow[2][2][4], lrow[2][2][4];
    #pragma unroll
    for (int hd = 0; hd < 2; ++hd)
        #pragma unroll
        for (int qt = 0; qt < 2; ++qt)
            #pragma unroll
            for (int r = 0; r < 4; ++r) { mrow[hd][qt][r] = -1e30f; lrow[hd][qt][r] = 0.f; }
    floatx4 accO[2][2][4] = {};

    int slot0 = tid, slot1 = tid + 256;
    int row0 = slot0 >> 3, g0 = (slot0 & 7) ^ (row0 & 7);
    int row1 = slot1 >> 3, g1 = (slot1 & 7) ^ (row1 & 7);
    const unsigned short* vtb = vT + ((size_t)(b * NKVV + kvh) * 64) * SEQ;

    // ---- valid-chunk bitmap (chunks 0..kc_end with doc overlap)
    int kc_end = 2 * qblk + 1;                    // <= 31
    unsigned mask;
    {
        bool v = false;
        if (lane <= kc_end && lane < 32)
            v = (docb[lane * 64 + 63] >= qd_blk);
        mask = (unsigned)__ballot(v);
    }

    auto stagec = [&](int buf, int kc) {
        int k0 = kc * 64;
        __builtin_amdgcn_global_load_lds(
            (gas_ptr)(kus + (size_t)(b * SEQ + k0 + row0) * QKVS + kvh * HDD + g0 * 8),
            (las_ptr)(&Ks[buf][slot0 * 8]), 16, 0, 0);
        __builtin_amdgcn_global_load_lds(
            (gas_ptr)(kus + (size_t)(b * SEQ + k0 + row1) * QKVS + kvh * HDD + g1 * 8),
            (las_ptr)(&Ks[buf][slot1 * 8]), 16, 0, 0);
        __builtin_amdgcn_global_load_lds(
            (gas_ptr)(vtb + (size_t)row0 * SEQ + k0 + g0 * 8),
            (las_ptr)(&Vts[buf][slot0 * 8]), 16, 0, 0);
        __builtin_amdgcn_global_load_lds(
            (gas_ptr)(vtb + (size_t)row1 * SEQ + k0 + g1 * 8),
            (las_ptr)(&Vts[buf][slot1 * 8]), 16, 0, 0);
        __builtin_amdgcn_global_load_lds(
            (gas_ptr)(docb + k0 + lane),
            (las_ptr)(&kdoc[buf][lane]), 4, 0, 0);
    };

    int p  = 0;
    int kc = (int)__builtin_ctz(mask);
    mask &= mask - 1;
    stagec(0, kc);

    while (true) {
        int nkc = -1;
        if (mask) {
            nkc = (int)__builtin_ctz(mask);
            mask &= mask - 1;
            stagec(p ^ 1, nkc);
            asm volatile("s_waitcnt vmcnt(5)" ::: "memory");
        } else {
            asm volatile("s_waitcnt vmcnt(0)" ::: "memory");
        }
        CBAR(); __builtin_amdgcn_s_barrier(); CBAR();

        int k0 = kc * 64;
        int kd_first = kdoc[p][0];
        int kd_last  = kdoc[p][63];
        if (k0 <= qw + 31 && kd_last >= qd_w) {   // wave-uniform compute skip
            bool full = qdu && (kd_first == kd_last) && (kd_last == qd_w)
                        && (k0 + 64 <= qw);

            // hoisted K/V fragments (16 ds_read_b128, shared by both heads)
            bf16x8 bk[4][2], bvf[4][2];
            #pragma unroll
            for (int t = 0; t < 4; ++t) {
                int krow = t * 16 + l15;
                bk[t][0]  = *reinterpret_cast<const bf16x8*>(&Ks[p][krow * 64 + ((l4 ^ (krow & 7)) * 8)]);
                bk[t][1]  = *reinterpret_cast<const bf16x8*>(&Ks[p][krow * 64 + (((l4 + 4) ^ (krow & 7)) * 8)]);
                bvf[t][0] = *reinterpret_cast<const bf16x8*>(&Vts[p][krow * 64 + ((l4 ^ (krow & 7)) * 8)]);
                bvf[t][1] = *reinterpret_cast<const bf16x8*>(&Vts[p][krow * 64 + (((l4 + 4) ^ (krow & 7)) * 8)]);
            }

            #pragma unroll
            for (int hd = 0; hd < 2; ++hd) {
                #pragma unroll
                for (int qt = 0; qt < 2; ++qt) {
                    float s[4][4];
                    #pragma unroll
                    for (int t = 0; t < 4; ++t) {
                        floatx4 a = {};
                        a = MFMA16(aq[hd][qt][0], bk[t][0], a, 0, 0, 0);
                        a = MFMA16(aq[hd][qt][1], bk[t][1], a, 0, 0, 0);
                        if (full) {
                            #pragma unroll
                            for (int r = 0; r < 4; ++r) s[t][r] = a[r] * SCL2;
                        } else {
                            int key = k0 + t * 16 + l15;
                            int kd  = kdoc[p][t * 16 + l15];
                            #pragma unroll
                            for (int r = 0; r < 4; ++r) {
                                int qrow = qw + qt * 16 + l4 * 4 + r;
                                bool valid = (kd == qd[qt][r]) && (key <= qrow);
                                s[t][r] = valid ? a[r] * SCL2 : MASKV;
                            }
                        }
                    }
                    #pragma unroll
                    for (int r = 0; r < 4; ++r) {
                        float pm = fmaxf(fmaxf(s[0][r], s[1][r]), fmaxf(s[2][r], s[3][r]));
                        pm = red16_max(pm);
                        float mnew = fmaxf(mrow[hd][qt][r], pm);
                        float alpha = EXP2F(mrow[hd][qt][r] - mnew);
                        mrow[hd][qt][r] = mnew;
                        float ps = 0.f;
                        #pragma unroll
                        for (int t = 0; t < 4; ++t) {
                            float pv = EXP2F(s[t][r] - mnew);   // masked -> underflow 0
                            Pb[wv][qt * 16 + l4 * 4 + r][t * 16 + l15] = f2bu(pv);
                            ps += pv;
                        }
                        ps = red16_sum(ps);
                        lrow[hd][qt][r] = lrow[hd][qt][r] * alpha + ps;
                        #pragma unroll
                        for (int t = 0; t < 4; ++t) accO[hd][qt][t][r] *= alpha;
                    }
                }
                #pragma unroll
                for (int qt = 0; qt < 2; ++qt) {
                    bf16x8 ap0 = *reinterpret_cast<const bf16x8*>(&Pb[wv][qt * 16 + l15][l4 * 8]);
                    bf16x8 ap1 = *reinterpret_cast<const bf16x8*>(&Pb[wv][qt * 16 + l15][32 + l4 * 8]);
                    #pragma unroll
                    for (int t = 0; t < 4; ++t) {
                        accO[hd][qt][t] = MFMA16(ap0, bvf[t][0], accO[hd][qt][t], 0, 0, 0);
                        accO[hd][qt][t] = MFMA16(ap1, bvf[t][1], accO[hd][qt][t], 0, 0, 0);
                    }
                }
            }
        }
        CBAR(); __builtin_amdgcn_s_barrier(); CBAR();
        if (nkc < 0) break;
        kc = nkc; p ^= 1;
    }

    #pragma unroll
    for (int hd = 0; hd < 2; ++hd)
        #pragma unroll
        for (int qt = 0; qt < 2; ++qt)
            #pragma unroll
            for (int r = 0; r < 4; ++r) {
                float inv = 1.0f / lrow[hd][qt][r];
                size_t base = (size_t)(b * SEQ + qw + qt * 16 + l4 * 4 + r) * (NHH * HDD) + (h0 + hd) * HDD;
                #pragma unroll
                for (int t = 0; t < 4; ++t)
                    ob[base + t * 16 + l15] = __float2bfloat16(accO[hd][qt][t][r] * inv);
            }
}

// ---------------------------------------------------------------------------
extern "C" void kernel_launch(void* const* d_in, const int* in_sizes, int n_in,
                              void* d_out, int out_size, void* d_ws, size_t ws_size,
                              hipStream_t stream) {
    const float* x  = (const float*)d_in[0];
    const float* rc = (const float*)d_in[1];
    const float* rs = (const float*)d_in[2];
    const int*   dc = (const int*)d_in[3];
    const float* Wq = (const float*)d_in[4];
    const float* Wk = (const float*)d_in[5];
    const float* Wv = (const float*)d_in[6];
    const float* Wo = (const float*)d_in[7];
    float* out = (float*)d_out;

    const int M    = BB * SEQ;        // 4096
    const int KVD  = NKVV * HDD;      // 512
    const int QKVN = DIMD + 2 * KVD;  // 3072

    char* ws = (char*)d_ws;
    size_t off = 0;
    auto alloc = [&](size_t elems) { __hip_bfloat16* p = (__hip_bfloat16*)(ws + off); off += elems * 2; return p; };
    __hip_bfloat16* xb   = alloc((size_t)M * DIMD);      // 16 MB
    __hip_bfloat16* wqkv = alloc((size_t)QKVN * DIMD);   // 12 MB
    __hip_bfloat16* wob  = alloc((size_t)DIMD * DIMD);   //  8 MB
    __hip_bfloat16* qkv  = alloc((size_t)M * QKVN);      // 24 MB (v-section unused)
    __hip_bfloat16* abuf = alloc((size_t)M * DIMD);      // 16 MB
    unsigned short* vtb  = (unsigned short*)alloc((size_t)BB * NKVV * HDD * SEQ); // 4 MB

    // one fused f32->bf16 conversion launch
    {
        unsigned total4 = (C_X + C_WQ + C_WK + C_WV + C_WO) / 4;
        cvt_all<<<dim3((total4 + 255) / 256), 256, 0, stream>>>(
            x, Wq, Wk, Wv, Wo, xb, wqkv, wob);
    }

    // fused QKV projection: RoPE epilogue + direct V-transpose to vT
    gemm32<__hip_bfloat16, true><<<dim3(M / 128, QKVN / 128), 256, 0, stream>>>(
        xb, wqkv, qkv, M, QKVN, DIMD, QKVN, rc, rs, vtb);

    // attention (MFMA, doc-skip, dbuf staging, DPP softmax, 2 heads/block)
    attn_mfma<<<dim3(SEQ / 128, NHH / 2, BB), 256, 0, stream>>>(qkv, vtb, dc, abuf);

    // output projection (f32 out)
    gemm32<float, false><<<dim3(M / 128, DIMD / 128), 256, 0, stream>>>(
        abuf, wob, out, M, DIMD, DIMD, DIMD, nullptr, nullptr, nullptr);
}

// Round 11
// 257.663 us; speedup vs baseline: 1.0860x; 1.0691x over previous
//
#include <hip/hip_runtime.h>
#include <hip/hip_bf16.h>

// Problem constants
#define BB   2
#define SEQ  2048
#define DIMD 2048
#define NHH  32
#define NKVV 8
#define HDD  64
#define QKVS 3072
// N_REP = 4

typedef __bf16 bf16x8 __attribute__((ext_vector_type(8)));
typedef float  floatx4  __attribute__((ext_vector_type(4)));
typedef float  floatx16 __attribute__((ext_vector_type(16)));

typedef __attribute__((address_space(1))) const void* gas_ptr;
typedef __attribute__((address_space(3))) void*       las_ptr;

#define MFMA16 __builtin_amdgcn_mfma_f32_16x16x32_bf16
#define MFMA32 __builtin_amdgcn_mfma_f32_32x32x16_bf16
#define CBAR() asm volatile("" ::: "memory")
#define EXP2F(x) __builtin_amdgcn_exp2f(x)

__device__ __forceinline__ unsigned short f2bu(float f) {
    __hip_bfloat16 h = __float2bfloat16(f);
    return *reinterpret_cast<unsigned short*>(&h);
}

// DPP lane-move within 16-lane rows (all lanes active).
#define DPPF(x, ctrl) __int_as_float(__builtin_amdgcn_mov_dpp(__float_as_int(x), (ctrl), 0xF, 0xF, true))
__device__ __forceinline__ float red16_max(float x) {
    x = fmaxf(x, DPPF(x, 0xB1));
    x = fmaxf(x, DPPF(x, 0x4E));
    x = fmaxf(x, DPPF(x, 0x124));
    x = fmaxf(x, DPPF(x, 0x128));
    return x;
}
__device__ __forceinline__ float red16_sum(float x) {
    x += DPPF(x, 0xB1);
    x += DPPF(x, 0x4E);
    x += DPPF(x, 0x124);
    x += DPPF(x, 0x128);
    return x;
}

// ---------------------------------------------------------------------------
// Fused f32 -> bf16 conversion for all 5 inputs (one launch).
// ---------------------------------------------------------------------------
#define C_X  (8u  * 1024 * 1024)
#define C_WQ (4u  * 1024 * 1024)
#define C_WK (1u  * 1024 * 1024)
#define C_WV (1u  * 1024 * 1024)
#define C_WO (4u  * 1024 * 1024)
__global__ void cvt_all(const float* __restrict__ x,  const float* __restrict__ wq,
                        const float* __restrict__ wk, const float* __restrict__ wv,
                        const float* __restrict__ wo,
                        __hip_bfloat16* __restrict__ xb,
                        __hip_bfloat16* __restrict__ wqkv,
                        __hip_bfloat16* __restrict__ wob)
{
    unsigned i = (blockIdx.x * blockDim.x + threadIdx.x) * 4;
    const float* src; __hip_bfloat16* dst;
    if (i < C_X)                       { src = x  + i;                    dst = xb + i; }
    else if (i < C_X + C_WQ)           { unsigned o = i - C_X;            src = wq + o; dst = wqkv + o; }
    else if (i < C_X + C_WQ + C_WK)    { unsigned o = i - C_X - C_WQ;     src = wk + o; dst = wqkv + C_WQ + o; }
    else if (i < C_X + C_WQ + C_WK + C_WV) { unsigned o = i - C_X - C_WQ - C_WK; src = wv + o; dst = wqkv + C_WQ + C_WK + o; }
    else                               { unsigned o = i - C_X - C_WQ - C_WK - C_WV; if (o >= C_WO) return; src = wo + o; dst = wob + o; }
    float4 v = *reinterpret_cast<const float4*>(src);
    dst[0] = __float2bfloat16(v.x);
    dst[1] = __float2bfloat16(v.y);
    dst[2] = __float2bfloat16(v.z);
    dst[3] = __float2bfloat16(v.w);
}

// ---------------------------------------------------------------------------
// GEMM (round-7 proven, 257.8 us config): 32x32x16 MFMA + BK=64, 128B rows,
// chunk swizzle ch = chL ^ (row&7), source pre-swizzled, linear gload dest.
// C[M,ldc] = A[M,K] @ W[N,K]^T, bf16 in, f32 acc. Wave-tile 64x64. LDS 32KB.
// ROPE=true: RoPE epilogue for cols < 2560 (q|k); cols >= 2560 (V) written
// TRANSPOSED directly to vT[b][kvh][d][s].
// C/D layout (HW-verified m74/m101): col=lane&31, row=(reg&3)+8*(reg>>2)+4*(lane>>5).
// ---------------------------------------------------------------------------
template <typename OutT, bool ROPE>
__global__ __launch_bounds__(256) void gemm32(
    const __hip_bfloat16* __restrict__ Abf,
    const __hip_bfloat16* __restrict__ Wbf,
    OutT* __restrict__ C,
    int M, int N, int K, int ldc,
    const float* __restrict__ cosb, const float* __restrict__ sinb,
    unsigned short* __restrict__ vT)
{
    const __bf16* A = reinterpret_cast<const __bf16*>(Abf);
    const __bf16* W = reinterpret_cast<const __bf16*>(Wbf);

    __shared__ __bf16 As[128 * 64];   // 16 KB
    __shared__ __bf16 Bs[128 * 64];   // 16 KB

    int tid  = threadIdx.x;
    int wid  = tid >> 6;
    int lane = tid & 63;
    int l31  = lane & 31;
    int lh   = lane >> 5;
    int wm   = (wid & 1) * 64;
    int wn   = (wid >> 1) * 64;
    int bm   = blockIdx.x * 128;
    int bn   = blockIdx.y * 128;

    // Staging: 4 x 16B loads per thread per matrix; LDS dest linear
    // (slot*16B); source chunk pre-XOR-swizzled with (row&7).
    const __bf16* aS[4]; const __bf16* wS[4];
    #pragma unroll
    for (int i = 0; i < 4; ++i) {
        int slot = tid + 256 * i;
        int r = slot >> 3;
        int c = (slot & 7) ^ (r & 7);
        aS[i] = A + (size_t)(bm + r) * K + c * 8;
        wS[i] = W + (size_t)(bn + r) * K + c * 8;
    }

    floatx16 acc[2][2] = {};

    for (int k0 = 0; k0 < K; k0 += 64) {
        #pragma unroll
        for (int i = 0; i < 4; ++i)
            __builtin_amdgcn_global_load_lds((gas_ptr)(aS[i] + k0),
                (las_ptr)(As + (tid + 256 * i) * 8), 16, 0, 0);
        #pragma unroll
        for (int i = 0; i < 4; ++i)
            __builtin_amdgcn_global_load_lds((gas_ptr)(wS[i] + k0),
                (las_ptr)(Bs + (tid + 256 * i) * 8), 16, 0, 0);
        __syncthreads();

        #pragma unroll
        for (int s = 0; s < 4; ++s) {            // 4 k-steps of 16
            bf16x8 af[2], bfr[2];
            #pragma unroll
            for (int mt = 0; mt < 2; ++mt) {
                int row = wm + mt * 32 + l31;
                int ch  = (s * 2 + lh) ^ (row & 7);
                af[mt] = *reinterpret_cast<const bf16x8*>(As + row * 64 + ch * 8);
            }
            #pragma unroll
            for (int nt = 0; nt < 2; ++nt) {
                int row = wn + nt * 32 + l31;
                int ch  = (s * 2 + lh) ^ (row & 7);
                bfr[nt] = *reinterpret_cast<const bf16x8*>(Bs + row * 64 + ch * 8);
            }
            #pragma unroll
            for (int mt = 0; mt < 2; ++mt)
                #pragma unroll
                for (int nt = 0; nt < 2; ++nt)
                    acc[mt][nt] = MFMA32(af[mt], bfr[nt], acc[mt][nt], 0, 0, 0);
        }
        __syncthreads();
    }

    const int col0 = bn + wn;
    if constexpr (ROPE) {
        if (col0 >= 2560) {
            // V section: write transposed directly to vT[b][kvh][d][s].
            int kvh = (col0 - 2560) >> 6;
            int b   = bm >> 11;
            #pragma unroll
            for (int mt = 0; mt < 2; ++mt)
                #pragma unroll
                for (int rq = 0; rq < 4; ++rq) {
                    int s0 = (bm & (SEQ - 1)) + wm + mt * 32 + rq * 8 + lh * 4;
                    #pragma unroll
                    for (int nt = 0; nt < 2; ++nt) {
                        int d = nt * 32 + l31;
                        ushort4 u;
                        u.x = f2bu(acc[mt][nt][rq * 4 + 0]);
                        u.y = f2bu(acc[mt][nt][rq * 4 + 1]);
                        u.z = f2bu(acc[mt][nt][rq * 4 + 2]);
                        u.w = f2bu(acc[mt][nt][rq * 4 + 3]);
                        *reinterpret_cast<ushort4*>(
                            vT + ((size_t)(b * NKVV + kvh) * 64 + d) * SEQ + s0) = u;
                    }
                }
        } else {
            // q|k section: RoPE pairs (d, d+32) = (acc[mt][0], acc[mt][1]), d = l31
            #pragma unroll
            for (int mt = 0; mt < 2; ++mt)
                #pragma unroll
                for (int reg = 0; reg < 16; ++reg) {
                    int row = bm + wm + mt * 32 + (reg & 3) + (reg >> 2) * 8 + lh * 4;
                    int s   = row & (SEQ - 1);
                    float x1 = acc[mt][0][reg], x2 = acc[mt][1][reg];
                    float cf = cosb[s * 32 + l31];
                    float sf = sinb[s * 32 + l31];
                    float o1 = x1 * cf - x2 * sf;
                    float o2 = x2 * cf + x1 * sf;
                    C[(size_t)row * ldc + col0 + l31]      = __float2bfloat16(o1);
                    C[(size_t)row * ldc + col0 + 32 + l31] = __float2bfloat16(o2);
                }
        }
    } else {
        #pragma unroll
        for (int mt = 0; mt < 2; ++mt)
            #pragma unroll
            for (int nt = 0; nt < 2; ++nt)
                #pragma unroll
                for (int reg = 0; reg < 16; ++reg) {
                    int row = bm + wm + mt * 32 + (reg & 3) + (reg >> 2) * 8 + lh * 4;
                    int col = col0 + nt * 32 + l31;
                    if constexpr (sizeof(OutT) == 4)
                        C[(size_t)row * ldc + col] = acc[mt][nt][reg];
                    else
                        C[(size_t)row * ldc + col] = __float2bfloat16(acc[mt][nt][reg]);
                }
    }
}

// ---------------------------------------------------------------------------
// MFMA flash attention, doc+causal. dbuf staging (counted vmcnt), hoisted
// K/V frags, DPP reductions, exp2 domain, -3e30 mask, full-valid fast path.
// (round-7 proven, 1 head/block)
// ---------------------------------------------------------------------------
#define SCL2 0.18033688f   // 0.125 * log2(e)
#define MASKV -3e30f

__global__ __launch_bounds__(256) void attn_mfma(
    const __hip_bfloat16* __restrict__ qkv,  // [B*S][3072]: q | k | (v unused)
    const unsigned short* __restrict__ vT,   // [B][NKV][64][S]
    const int* __restrict__ doc,             // [B][S]
    __hip_bfloat16* __restrict__ ob)         // [B*S][NH*64]
{
    int qblk = (int)gridDim.x - 1 - (int)blockIdx.x;   // heavy blocks first
    int h    = blockIdx.y;
    int b    = blockIdx.z;
    int kvh  = h >> 2;
    int tid  = threadIdx.x;
    int wv   = tid >> 6;
    int lane = tid & 63;
    int l15  = lane & 15;
    int l4   = lane >> 4;
    int q0   = qblk * 128;
    int qw   = q0 + wv * 32;

    __shared__ unsigned short Ks[2][64 * 64];    // [key][dim], swizzled chunks
    __shared__ unsigned short Vts[2][64 * 64];   // [dim][key], swizzled chunks
    __shared__ int            kdoc[2][64];
    __shared__ unsigned short Pb[4][32][76];     // per-wave P tile

    const unsigned short* qus = reinterpret_cast<const unsigned short*>(qkv);
    const unsigned short* kus = qus + 2048;
    const int* docb = doc + b * SEQ;

    bf16x8 aq[2][2];
    #pragma unroll
    for (int qt = 0; qt < 2; ++qt) {
        const unsigned short* qrow = qus + (size_t)(b * SEQ + qw + qt * 16 + l15) * QKVS + h * HDD;
        aq[qt][0] = *reinterpret_cast<const bf16x8*>(qrow + l4 * 8);
        aq[qt][1] = *reinterpret_cast<const bf16x8*>(qrow + 32 + l4 * 8);
    }
    int qd[2][4];
    #pragma unroll
    for (int qt = 0; qt < 2; ++qt)
        #pragma unroll
        for (int r = 0; r < 4; ++r)
            qd[qt][r] = docb[qw + qt * 16 + l4 * 4 + r];
    int qd_w   = docb[qw];
    int qd_w31 = docb[qw + 31];
    int qd_blk = docb[q0];
    bool qdu   = (qd_w == qd_w31);

    float mrow[2][4], lrow[2][4];
    #pragma unroll
    for (int qt = 0; qt < 2; ++qt)
        #pragma unroll
        for (int r = 0; r < 4; ++r) { mrow[qt][r] = -1e30f; lrow[qt][r] = 0.f; }
    floatx4 accO[2][4] = {};

    int slot0 = tid, slot1 = tid + 256;
    int row0 = slot0 >> 3, g0 = (slot0 & 7) ^ (row0 & 7);
    int row1 = slot1 >> 3, g1 = (slot1 & 7) ^ (row1 & 7);
    const unsigned short* vtb = vT + ((size_t)(b * NKVV + kvh) * 64) * SEQ;

    // ---- valid-chunk bitmap (chunks 0..kc_end with doc overlap)
    int kc_end = 2 * qblk + 1;                    // <= 31
    unsigned mask;
    {
        bool v = false;
        if (lane <= kc_end && lane < 32)
            v = (docb[lane * 64 + 63] >= qd_blk);
        mask = (unsigned)__ballot(v);
    }

    auto stagec = [&](int buf, int kc) {
        int k0 = kc * 64;
        __builtin_amdgcn_global_load_lds(
            (gas_ptr)(kus + (size_t)(b * SEQ + k0 + row0) * QKVS + kvh * HDD + g0 * 8),
            (las_ptr)(&Ks[buf][slot0 * 8]), 16, 0, 0);
        __builtin_amdgcn_global_load_lds(
            (gas_ptr)(kus + (size_t)(b * SEQ + k0 + row1) * QKVS + kvh * HDD + g1 * 8),
            (las_ptr)(&Ks[buf][slot1 * 8]), 16, 0, 0);
        __builtin_amdgcn_global_load_lds(
            (gas_ptr)(vtb + (size_t)row0 * SEQ + k0 + g0 * 8),
            (las_ptr)(&Vts[buf][slot0 * 8]), 16, 0, 0);
        __builtin_amdgcn_global_load_lds(
            (gas_ptr)(vtb + (size_t)row1 * SEQ + k0 + g1 * 8),
            (las_ptr)(&Vts[buf][slot1 * 8]), 16, 0, 0);
        __builtin_amdgcn_global_load_lds(
            (gas_ptr)(docb + k0 + lane),
            (las_ptr)(&kdoc[buf][lane]), 4, 0, 0);
    };

    int p  = 0;
    int kc = (int)__builtin_ctz(mask);
    mask &= mask - 1;
    stagec(0, kc);

    while (true) {
        int nkc = -1;
        if (mask) {
            nkc = (int)__builtin_ctz(mask);
            mask &= mask - 1;
            stagec(p ^ 1, nkc);
            asm volatile("s_waitcnt vmcnt(5)" ::: "memory");
        } else {
            asm volatile("s_waitcnt vmcnt(0)" ::: "memory");
        }
        CBAR(); __builtin_amdgcn_s_barrier(); CBAR();

        int k0 = kc * 64;
        int kd_first = kdoc[p][0];
        int kd_last  = kdoc[p][63];
        if (k0 <= qw + 31 && kd_last >= qd_w) {   // wave-uniform compute skip
            bool full = qdu && (kd_first == kd_last) && (kd_last == qd_w)
                        && (k0 + 64 <= qw);

            // hoisted K fragments (8 ds_read_b128, shared by both qt)
            bf16x8 bk[4][2];
            #pragma unroll
            for (int t = 0; t < 4; ++t) {
                int krow = t * 16 + l15;
                bk[t][0] = *reinterpret_cast<const bf16x8*>(&Ks[p][krow * 64 + ((l4 ^ (krow & 7)) * 8)]);
                bk[t][1] = *reinterpret_cast<const bf16x8*>(&Ks[p][krow * 64 + (((l4 + 4) ^ (krow & 7)) * 8)]);
            }

            #pragma unroll
            for (int qt = 0; qt < 2; ++qt) {
                float s[4][4];
                #pragma unroll
                for (int t = 0; t < 4; ++t) {
                    floatx4 a = {};
                    a = MFMA16(aq[qt][0], bk[t][0], a, 0, 0, 0);
                    a = MFMA16(aq[qt][1], bk[t][1], a, 0, 0, 0);
                    if (full) {
                        #pragma unroll
                        for (int r = 0; r < 4; ++r) s[t][r] = a[r] * SCL2;
                    } else {
                        int key = k0 + t * 16 + l15;
                        int kd  = kdoc[p][t * 16 + l15];
                        #pragma unroll
                        for (int r = 0; r < 4; ++r) {
                            int qrow = qw + qt * 16 + l4 * 4 + r;
                            bool valid = (kd == qd[qt][r]) && (key <= qrow);
                            s[t][r] = valid ? a[r] * SCL2 : MASKV;
                        }
                    }
                }
                #pragma unroll
                for (int r = 0; r < 4; ++r) {
                    float pm = fmaxf(fmaxf(s[0][r], s[1][r]), fmaxf(s[2][r], s[3][r]));
                    pm = red16_max(pm);
                    float mnew = fmaxf(mrow[qt][r], pm);
                    float alpha = EXP2F(mrow[qt][r] - mnew);
                    mrow[qt][r] = mnew;
                    float ps = 0.f;
                    #pragma unroll
                    for (int t = 0; t < 4; ++t) {
                        float pv = EXP2F(s[t][r] - mnew);   // masked -> underflow 0
                        Pb[wv][qt * 16 + l4 * 4 + r][t * 16 + l15] = f2bu(pv);
                        ps += pv;
                    }
                    ps = red16_sum(ps);
                    lrow[qt][r] = lrow[qt][r] * alpha + ps;
                    #pragma unroll
                    for (int t = 0; t < 4; ++t) accO[qt][t][r] *= alpha;
                }
            }

            // hoisted V fragments (8 ds_read_b128, shared by both qt)
            bf16x8 bvf[4][2];
            #pragma unroll
            for (int t = 0; t < 4; ++t) {
                int vrow = t * 16 + l15;
                bvf[t][0] = *reinterpret_cast<const bf16x8*>(&Vts[p][vrow * 64 + ((l4 ^ (vrow & 7)) * 8)]);
                bvf[t][1] = *reinterpret_cast<const bf16x8*>(&Vts[p][vrow * 64 + (((l4 + 4) ^ (vrow & 7)) * 8)]);
            }
            #pragma unroll
            for (int qt = 0; qt < 2; ++qt) {
                bf16x8 ap0 = *reinterpret_cast<const bf16x8*>(&Pb[wv][qt * 16 + l15][l4 * 8]);
                bf16x8 ap1 = *reinterpret_cast<const bf16x8*>(&Pb[wv][qt * 16 + l15][32 + l4 * 8]);
                #pragma unroll
                for (int t = 0; t < 4; ++t) {
                    accO[qt][t] = MFMA16(ap0, bvf[t][0], accO[qt][t], 0, 0, 0);
                    accO[qt][t] = MFMA16(ap1, bvf[t][1], accO[qt][t], 0, 0, 0);
                }
            }
        }
        CBAR(); __builtin_amdgcn_s_barrier(); CBAR();
        if (nkc < 0) break;
        kc = nkc; p ^= 1;
    }

    #pragma unroll
    for (int qt = 0; qt < 2; ++qt)
        #pragma unroll
        for (int r = 0; r < 4; ++r) {
            float inv = 1.0f / lrow[qt][r];
            size_t base = (size_t)(b * SEQ + qw + qt * 16 + l4 * 4 + r) * (NHH * HDD) + h * HDD;
            #pragma unroll
            for (int t = 0; t < 4; ++t)
                ob[base + t * 16 + l15] = __float2bfloat16(accO[qt][t][r] * inv);
        }
}

// ---------------------------------------------------------------------------
extern "C" void kernel_launch(void* const* d_in, const int* in_sizes, int n_in,
                              void* d_out, int out_size, void* d_ws, size_t ws_size,
                              hipStream_t stream) {
    const float* x  = (const float*)d_in[0];
    const float* rc = (const float*)d_in[1];
    const float* rs = (const float*)d_in[2];
    const int*   dc = (const int*)d_in[3];
    const float* Wq = (const float*)d_in[4];
    const float* Wk = (const float*)d_in[5];
    const float* Wv = (const float*)d_in[6];
    const float* Wo = (const float*)d_in[7];
    float* out = (float*)d_out;

    const int M    = BB * SEQ;        // 4096
    const int KVD  = NKVV * HDD;      // 512
    const int QKVN = DIMD + 2 * KVD;  // 3072

    char* ws = (char*)d_ws;
    size_t off = 0;
    auto alloc = [&](size_t elems) { __hip_bfloat16* p = (__hip_bfloat16*)(ws + off); off += elems * 2; return p; };
    __hip_bfloat16* xb   = alloc((size_t)M * DIMD);      // 16 MB
    __hip_bfloat16* wqkv = alloc((size_t)QKVN * DIMD);   // 12 MB
    __hip_bfloat16* wob  = alloc((size_t)DIMD * DIMD);   //  8 MB
    __hip_bfloat16* qkv  = alloc((size_t)M * QKVN);      // 24 MB (v-section unused)
    __hip_bfloat16* abuf = alloc((size_t)M * DIMD);      // 16 MB
    unsigned short* vtb  = (unsigned short*)alloc((size_t)BB * NKVV * HDD * SEQ); // 4 MB

    // one fused f32->bf16 conversion launch
    {
        unsigned total4 = (C_X + C_WQ + C_WK + C_WV + C_WO) / 4;
        cvt_all<<<dim3((total4 + 255) / 256), 256, 0, stream>>>(
            x, Wq, Wk, Wv, Wo, xb, wqkv, wob);
    }

    // fused QKV projection: RoPE epilogue + direct V-transpose to vT
    gemm32<__hip_bfloat16, true><<<dim3(M / 128, QKVN / 128), 256, 0, stream>>>(
        xb, wqkv, qkv, M, QKVN, DIMD, QKVN, rc, rs, vtb);

    // attention (MFMA, doc-skip, dbuf staging, DPP softmax)
    attn_mfma<<<dim3(SEQ / 128, NHH, BB), 256, 0, stream>>>(qkv, vtb, dc, abuf);

    // output projection (f32 out)
    gemm32<float, false><<<dim3(M / 128, DIMD / 128), 256, 0, stream>>>(
        abuf, wob, out, M, DIMD, DIMD, DIMD, nullptr, nullptr, nullptr);
}